// Round 1
// baseline (129.653 us; speedup 1.0000x reference)
//
#include <hip/hip_runtime.h>
#include <hip/hip_bf16.h>

// out = (Q K^T * SCALE) @ V  ==  Q @ (SCALE * K^T V)   (softmax discarded in ref)
// B=32, T=2048, E=1024, H=64.  M = B*T = 65536.

using bf16x8 = __attribute__((ext_vector_type(8))) short;
using f32x4  = __attribute__((ext_vector_type(4))) float;
using u32x4  = __attribute__((ext_vector_type(4))) unsigned int;
using u32x2  = __attribute__((ext_vector_type(2))) unsigned int;
using u16    = unsigned short;

__device__ __forceinline__ u16 f2bf(float f) {
    unsigned u = __builtin_bit_cast(unsigned, f);
    u += 0x7fffu + ((u >> 16) & 1u);          // RNE
    return (u16)(u >> 16);
}
__device__ __forceinline__ float bflo(unsigned u) { return __builtin_bit_cast(float, u << 16); }
__device__ __forceinline__ float bfhi(unsigned u) { return __builtin_bit_cast(float, u & 0xffff0000u); }

// ---------------- k_wt: WT[n][e] = W*[e][n] as bf16, n in [0,192) ----------------
__global__ __launch_bounds__(256) void k_wt(const float* __restrict__ Wq,
                                            const float* __restrict__ Wk,
                                            const float* __restrict__ Wv,
                                            u16* __restrict__ WT) {
    const int n = blockIdx.x;                 // 0..191
    const int seg = n >> 6, col = n & 63;
    const float* W = (seg == 0) ? Wq : (seg == 1) ? Wk : Wv;
    const int tid = threadIdx.x;
#pragma unroll
    for (int p = 0; p < 4; ++p) {
        const int e = tid + p * 256;
        WT[n * 1024 + e] = f2bf(W[e * 64 + col]);
    }
}

// ---------------- k_qkv: Q|K|V = x @ [Wq|Wk|Wv] + bias, bf16 out ----------------
// block: 256 thr (4 waves), M-tile 128 rows, N = 192. K-chunks of 64.
__global__ __launch_bounds__(256) void k_qkv(const float* __restrict__ x,
                                             const u16* __restrict__ WT,
                                             const float* __restrict__ bq,
                                             const float* __restrict__ bk,
                                             const float* __restrict__ bv,
                                             u16* __restrict__ Qb,
                                             u16* __restrict__ Kb,
                                             u16* __restrict__ Vb) {
    __shared__ u16 xs[128 * 64];              // 16 KB, XOR-swizzled
    __shared__ u16 ws[192 * 64];              // 24 KB, XOR-swizzled
    const int tid  = threadIdx.x;
    const int wave = tid >> 6, lane = tid & 63;
    const size_t row0 = (size_t)blockIdx.x * 128;

    f32x4 acc[2][12];
#pragma unroll
    for (int mt = 0; mt < 2; ++mt)
#pragma unroll
        for (int nt = 0; nt < 12; ++nt)
#pragma unroll
            for (int r = 0; r < 4; ++r) acc[mt][nt][r] = 0.0f;

    char* const xsb = (char*)xs;
    char* const wsb = (char*)ws;
    const int xr = tid >> 4;                  // x staging: row base
    const int xc = (tid & 15) * 4;            // x staging: col (elems)
    const int wn = tid >> 3;                  // WT staging: row base
    const int wslot = tid & 7;                // WT staging: 16B slot

    for (int kc = 0; kc < 16; ++kc) {
        const int k0 = kc * 64;
        // stage x tile: f32 -> bf16, swizzled write
#pragma unroll
        for (int p = 0; p < 8; ++p) {
            const int r = xr + 16 * p;
            const f32x4 v = *(const f32x4*)(x + (row0 + r) * 1024 + k0 + xc);
            u32x2 pk;
            pk[0] = (unsigned)f2bf(v[0]) | ((unsigned)f2bf(v[1]) << 16);
            pk[1] = (unsigned)f2bf(v[2]) | ((unsigned)f2bf(v[3]) << 16);
            int byte = r * 128 + xc * 2;
            byte ^= (r & 7) << 4;
            *(u32x2*)(xsb + byte) = pk;
        }
        // stage W^T tile: bf16 copy, swizzled write
#pragma unroll
        for (int p = 0; p < 6; ++p) {
            const int n = wn + 32 * p;
            const u32x4 v = *(const u32x4*)(WT + n * 1024 + k0 + wslot * 8);
            int byte = n * 128 + wslot * 16;
            byte ^= (n & 7) << 4;
            *(u32x4*)(wsb + byte) = v;
        }
        __syncthreads();
#pragma unroll
        for (int ks = 0; ks < 2; ++ks) {
            bf16x8 af[2];
#pragma unroll
            for (int mt = 0; mt < 2; ++mt) {
                const int r = wave * 32 + mt * 16 + (lane & 15);
                int byte = r * 128 + ((lane >> 4) * 8 + ks * 32) * 2;
                byte ^= (r & 7) << 4;
                af[mt] = *(const bf16x8*)(xsb + byte);
            }
#pragma unroll
            for (int nt = 0; nt < 12; ++nt) {
                const int n = nt * 16 + (lane & 15);
                int byte = n * 128 + ((lane >> 4) * 8 + ks * 32) * 2;
                byte ^= (n & 7) << 4;
                const bf16x8 bfr = *(const bf16x8*)(wsb + byte);
                acc[0][nt] = __builtin_amdgcn_mfma_f32_16x16x32_bf16(af[0], bfr, acc[0][nt], 0, 0, 0);
                acc[1][nt] = __builtin_amdgcn_mfma_f32_16x16x32_bf16(af[1], bfr, acc[1][nt], 0, 0, 0);
            }
        }
        __syncthreads();
    }

    // epilogue: +bias, cvt bf16, store. D-layout: col=lane&15, row=(lane>>4)*4+rr
#pragma unroll
    for (int nt = 0; nt < 12; ++nt) {
        const int seg = nt >> 2;
        const int col = (nt & 3) * 16 + (lane & 15);
        const float bias = ((seg == 0) ? bq : (seg == 1) ? bk : bv)[col];
        u16* const dst = (seg == 0) ? Qb : (seg == 1) ? Kb : Vb;
#pragma unroll
        for (int mt = 0; mt < 2; ++mt) {
            const size_t rbase = row0 + wave * 32 + mt * 16 + ((lane >> 4) << 2);
#pragma unroll
            for (int rr = 0; rr < 4; ++rr)
                dst[(rbase + rr) * 64 + col] = f2bf(acc[mt][nt][rr] + bias);
        }
    }
}

// ---------------- k_ktv: partial K^T V per (b, T-chunk of 128) ----------------
__global__ __launch_bounds__(256) void k_ktv(const u16* __restrict__ Kb,
                                             const u16* __restrict__ Vb,
                                             float* __restrict__ part) {
    __shared__ float Ks[64][64];
    __shared__ float Vs[64][64];
    const int tid = threadIdx.x;
    const int b = blockIdx.x >> 4, c = blockIdx.x & 15;
    const int i0 = (tid >> 4) * 4, j0 = (tid & 15) * 4;
    float acc[4][4];
#pragma unroll
    for (int i = 0; i < 4; ++i)
#pragma unroll
        for (int j = 0; j < 4; ++j) acc[i][j] = 0.0f;

    const int tr = tid >> 2, sc0 = (tid & 3) * 16;
    const size_t base = ((size_t)b * 2048 + c * 128) * 64;

    for (int sc = 0; sc < 2; ++sc) {
        const size_t src = base + (size_t)(sc * 64 + tr) * 64 + sc0;
        const u32x4 ka = *(const u32x4*)(Kb + src);
        const u32x4 kc2 = *(const u32x4*)(Kb + src + 8);
        const u32x4 va = *(const u32x4*)(Vb + src);
        const u32x4 vc2 = *(const u32x4*)(Vb + src + 8);
#pragma unroll
        for (int w = 0; w < 4; ++w) {
            Ks[tr][sc0 + 2 * w]         = bflo(ka[w]);
            Ks[tr][sc0 + 2 * w + 1]     = bfhi(ka[w]);
            Ks[tr][sc0 + 8 + 2 * w]     = bflo(kc2[w]);
            Ks[tr][sc0 + 8 + 2 * w + 1] = bfhi(kc2[w]);
            Vs[tr][sc0 + 2 * w]         = bflo(va[w]);
            Vs[tr][sc0 + 2 * w + 1]     = bfhi(va[w]);
            Vs[tr][sc0 + 8 + 2 * w]     = bflo(vc2[w]);
            Vs[tr][sc0 + 8 + 2 * w + 1] = bfhi(vc2[w]);
        }
        __syncthreads();
#pragma unroll 4
        for (int t = 0; t < 64; ++t) {
            const f32x4 kv = *(const f32x4*)&Ks[t][i0];
            const f32x4 vv = *(const f32x4*)&Vs[t][j0];
#pragma unroll
            for (int i = 0; i < 4; ++i)
#pragma unroll
                for (int j = 0; j < 4; ++j) acc[i][j] += kv[i] * vv[j];
        }
        __syncthreads();
    }
    float* const P = part + (size_t)blockIdx.x * 4096;
#pragma unroll
    for (int i = 0; i < 4; ++i)
#pragma unroll
        for (int j = 0; j < 4; ++j)
            P[(i0 + i) * 64 + j0 + j] = acc[i][j];
}

// ---------------- k_red: KtVT[b][n][h] = SCALE * sum_c part[b,c][h][n], bf16 ----------------
__global__ __launch_bounds__(256) void k_red(const float* __restrict__ part,
                                             u16* __restrict__ KtVT) {
    const int b = blockIdx.x;
    const int tid = threadIdx.x;
    const float* const Pb = part + (size_t)b * 16 * 4096;
#pragma unroll
    for (int e = 0; e < 16; ++e) {
        const int o = tid * 16 + e;
        const int n = o >> 6, h = o & 63;
        float s = 0.0f;
#pragma unroll
        for (int c = 0; c < 16; ++c) s += Pb[c * 4096 + h * 64 + n];
        KtVT[(size_t)b * 4096 + o] = f2bf(s * 0.125f);   // SCALE = 64^-0.5
    }
}

// ---------------- k_out: out = Q @ KtV (K=64), fp32 out ----------------
__global__ __launch_bounds__(256) void k_out(const u16* __restrict__ Qb,
                                             const u16* __restrict__ KtVT,
                                             float* __restrict__ out) {
    const int tid = threadIdx.x;
    const int wave = tid >> 6, lane = tid & 63;
    const size_t m0 = (size_t)blockIdx.x * 64 + wave * 16;
    const int b = blockIdx.x >> 5;            // 32 blocks per batch
    const u16* const Bp = KtVT + (size_t)b * 4096;

    bf16x8 bfrag[2][4];
#pragma unroll
    for (int ks = 0; ks < 2; ++ks)
#pragma unroll
        for (int nt = 0; nt < 4; ++nt)
            bfrag[ks][nt] = *(const bf16x8*)(Bp + (nt * 16 + (lane & 15)) * 64 + ks * 32 + (lane >> 4) * 8);

    f32x4 acc[4];
#pragma unroll
    for (int nt = 0; nt < 4; ++nt)
#pragma unroll
        for (int r = 0; r < 4; ++r) acc[nt][r] = 0.0f;

#pragma unroll
    for (int ks = 0; ks < 2; ++ks) {
        const bf16x8 a = *(const bf16x8*)(Qb + (m0 + (lane & 15)) * 64 + ks * 32 + (lane >> 4) * 8);
#pragma unroll
        for (int nt = 0; nt < 4; ++nt)
            acc[nt] = __builtin_amdgcn_mfma_f32_16x16x32_bf16(a, bfrag[ks][nt], acc[nt], 0, 0, 0);
    }
#pragma unroll
    for (int nt = 0; nt < 4; ++nt)
#pragma unroll
        for (int rr = 0; rr < 4; ++rr)
            out[(m0 + (lane >> 4) * 4 + rr) * 64 + nt * 16 + (lane & 15)] = acc[nt][rr];
}

extern "C" void kernel_launch(void* const* d_in, const int* in_sizes, int n_in,
                              void* d_out, int out_size, void* d_ws, size_t ws_size,
                              hipStream_t stream) {
    (void)in_sizes; (void)n_in; (void)out_size; (void)ws_size;
    const float* x  = (const float*)d_in[0];
    const float* Wq = (const float*)d_in[1];
    const float* bq = (const float*)d_in[2];
    const float* Wk = (const float*)d_in[3];
    const float* bk = (const float*)d_in[4];
    const float* Wv = (const float*)d_in[5];
    const float* bv = (const float*)d_in[6];
    float* out = (float*)d_out;

    char* ws = (char*)d_ws;                       // layout (34.2 MB total):
    u16*  WT   = (u16*)(ws);                      // 0x0000000: 384 KB  WT bf16 [192][1024]
    u16*  Qb   = (u16*)(ws + 0x60000);            // 0x0060000: 8 MB    Q bf16 [65536][64]
    u16*  Kb   = (u16*)(ws + 0x860000);           // 0x0860000: 8 MB    K bf16
    u16*  Vb   = (u16*)(ws + 0x1060000);          // 0x1060000: 8 MB    V bf16
    float* part= (float*)(ws + 0x1860000);        // 0x1860000: 8 MB    partials [512][64][64] f32
    u16*  KtVT = (u16*)(ws + 0x2060000);          // 0x2060000: 256 KB  KtV^T bf16 [32][64][64]

    k_wt <<<192,  256, 0, stream>>>(Wq, Wk, Wv, WT);
    k_qkv<<<512,  256, 0, stream>>>(x, WT, bq, bk, bv, Qb, Kb, Vb);
    k_ktv<<<512,  256, 0, stream>>>(Kb, Vb, part);
    k_red<<<32,   256, 0, stream>>>(part, KtVT);
    k_out<<<1024, 256, 0, stream>>>(Qb, KtVT, out);
}

// Round 2
// 105.177 us; speedup vs baseline: 1.2327x; 1.2327x over previous
//
#include <hip/hip_runtime.h>
#include <hip/hip_bf16.h>

// out = (Q K^T * SCALE) @ V  ==  Q @ (SCALE * K^T V)   (softmax discarded in ref)
// B=32, T=2048, E=1024, H=64.  M = B*T = 65536.

using bf16x8 = __attribute__((ext_vector_type(8))) short;
using f32x4  = __attribute__((ext_vector_type(4))) float;
using u32x4  = __attribute__((ext_vector_type(4))) unsigned int;
using u32x2  = __attribute__((ext_vector_type(2))) unsigned int;
using u16    = unsigned short;

__device__ __forceinline__ u16 f2bf(float f) {
    unsigned u = __builtin_bit_cast(unsigned, f);
    u += 0x7fffu + ((u >> 16) & 1u);          // RNE
    return (u16)(u >> 16);
}
__device__ __forceinline__ float bflo(unsigned u) { return __builtin_bit_cast(float, u << 16); }
__device__ __forceinline__ float bfhi(unsigned u) { return __builtin_bit_cast(float, u & 0xffff0000u); }

#define G2L16(g, l) __builtin_amdgcn_global_load_lds(                         \
    (const __attribute__((address_space(1))) void*)(g),                       \
    (__attribute__((address_space(3))) void*)(l), 16, 0, 0)

// ---------------- k_wt: WT[n][e] = W*[e][n] as bf16, n in [0,192) ----------------
__global__ __launch_bounds__(256) void k_wt(const float* __restrict__ Wq,
                                            const float* __restrict__ Wk,
                                            const float* __restrict__ Wv,
                                            u16* __restrict__ WT) {
    const int n = blockIdx.x;                 // 0..191
    const int seg = n >> 6, col = n & 63;
    const float* W = (seg == 0) ? Wq : (seg == 1) ? Wk : Wv;
    const int tid = threadIdx.x;
#pragma unroll
    for (int p = 0; p < 4; ++p) {
        const int e = tid + p * 256;
        WT[n * 1024 + e] = f2bf(W[e * 64 + col]);
    }
}

// ---------------- k_qkv: Q|K|V = x @ [Wq|Wk|Wv] + bias, bf16 out ----------------
// 512 thr (8 waves), M-tile 128, N=192, BK=64.  gload_lds + dbuf + counted vmcnt.
// LDS per buf: x f32 [128][64] (32 KB, swz ^((r&7)<<5)) + WT bf16 [192][64]
// (24 KB, swz ^((n&7)<<4)).  Sources pre-swizzled so DMA dest stays linear.
__global__ __launch_bounds__(512, 2) void k_qkv(const float* __restrict__ x,
                                                const u16* __restrict__ WT,
                                                const float* __restrict__ bq,
                                                const float* __restrict__ bk,
                                                const float* __restrict__ bv,
                                                u16* __restrict__ Qb,
                                                u16* __restrict__ Kb,
                                                u16* __restrict__ Vb) {
    __shared__ char lds[2 * 57344];
    const int tid  = threadIdx.x;
    const int wave = tid >> 6, lane = tid & 63;
    const int wr = wave >> 1, wc = wave & 1;      // 4M x 2N wave grid
    const size_t row0 = (size_t)blockIdx.x * 128;

    // staging sources (element offsets), fixed per lane; +k0 per chunk
    size_t xsrc[4]; int xdst[4];
#pragma unroll
    for (int i = 0; i < 4; ++i) {
        const int r  = wave * 16 + i * 4 + (lane >> 4);
        const int cb = ((lane & 15) * 16) ^ ((r & 7) << 5);
        xsrc[i] = (row0 + r) * 1024 + (cb >> 2);
        xdst[i] = wave * 4096 + i * 1024;
    }
    size_t wsrc[3]; int wdst[3];
#pragma unroll
    for (int j = 0; j < 3; ++j) {
        const int n  = wave * 24 + j * 8 + (lane >> 3);
        const int cb = ((lane & 7) * 16) ^ ((n & 7) << 4);
        wsrc[j] = (size_t)n * 1024 + (cb >> 1);
        wdst[j] = 32768 + wave * 3072 + j * 1024;
    }

    f32x4 acc[2][6];
#pragma unroll
    for (int m = 0; m < 2; ++m)
#pragma unroll
        for (int n = 0; n < 6; ++n)
#pragma unroll
            for (int r = 0; r < 4; ++r) acc[m][n][r] = 0.0f;

    // prologue: stage tile 0 into buf 0
#pragma unroll
    for (int i = 0; i < 4; ++i) G2L16(x + xsrc[i], lds + xdst[i]);
#pragma unroll
    for (int j = 0; j < 3; ++j) G2L16(WT + wsrc[j], lds + wdst[j]);

    for (int kc = 0; kc < 16; ++kc) {
        const int cur = kc & 1;
        if (kc < 15) {                            // stage next tile, keep 7 in flight
            const int k0 = (kc + 1) * 64;
            char* base = lds + (cur ^ 1) * 57344;
#pragma unroll
            for (int i = 0; i < 4; ++i) G2L16(x + xsrc[i] + k0, base + xdst[i]);
#pragma unroll
            for (int j = 0; j < 3; ++j) G2L16(WT + wsrc[j] + k0, base + wdst[j]);
            asm volatile("s_waitcnt vmcnt(7)" ::: "memory");   // current tile done
        } else {
            asm volatile("s_waitcnt vmcnt(0)" ::: "memory");
        }
        __builtin_amdgcn_s_barrier();
        __builtin_amdgcn_sched_barrier(0);

        const char* xb = lds + cur * 57344;
        const char* wb = xb + 32768;
#pragma unroll
        for (int ks = 0; ks < 2; ++ks) {
            bf16x8 af[2];
#pragma unroll
            for (int m = 0; m < 2; ++m) {
                const int r = wr * 32 + m * 16 + (lane & 15);
                const int P = (r * 256 + ks * 128 + (lane >> 4) * 32) ^ ((r & 7) << 5);
                const f32x4 lo = *(const f32x4*)(xb + P);
                const f32x4 hi = *(const f32x4*)(xb + P + 16);
                u32x4 pk;
                pk[0] = (unsigned)f2bf(lo[0]) | ((unsigned)f2bf(lo[1]) << 16);
                pk[1] = (unsigned)f2bf(lo[2]) | ((unsigned)f2bf(lo[3]) << 16);
                pk[2] = (unsigned)f2bf(hi[0]) | ((unsigned)f2bf(hi[1]) << 16);
                pk[3] = (unsigned)f2bf(hi[2]) | ((unsigned)f2bf(hi[3]) << 16);
                af[m] = __builtin_bit_cast(bf16x8, pk);
            }
#pragma unroll
            for (int n = 0; n < 6; ++n) {
                const int nn = wc * 96 + n * 16 + (lane & 15);
                const int P  = (nn * 128 + ks * 64 + (lane >> 4) * 16) ^ ((nn & 7) << 4);
                const bf16x8 bfr = *(const bf16x8*)(wb + P);
                acc[0][n] = __builtin_amdgcn_mfma_f32_16x16x32_bf16(af[0], bfr, acc[0][n], 0, 0, 0);
                acc[1][n] = __builtin_amdgcn_mfma_f32_16x16x32_bf16(af[1], bfr, acc[1][n], 0, 0, 0);
            }
        }
        __builtin_amdgcn_sched_barrier(0);
        __builtin_amdgcn_s_barrier();             // all reads of buf[cur] done
    }

    // epilogue: +bias, cvt bf16, store. D-layout: col=lane&15, row=(lane>>4)*4+rr
#pragma unroll
    for (int n = 0; n < 6; ++n) {
        const int ncol = wc * 96 + n * 16 + (lane & 15);
        const int seg = ncol >> 6, col = ncol & 63;
        const float bias = ((seg == 0) ? bq : (seg == 1) ? bk : bv)[col];
        u16* const dst = (seg == 0) ? Qb : (seg == 1) ? Kb : Vb;
#pragma unroll
        for (int m = 0; m < 2; ++m) {
            const size_t rbase = row0 + wr * 32 + m * 16 + ((lane >> 4) << 2);
#pragma unroll
            for (int rr = 0; rr < 4; ++rr)
                dst[(rbase + rr) * 64 + col] = f2bf(acc[m][n][rr] + bias);
        }
    }
}

// ---------------- k_ktv: partial K^T V per (b, 64-row chunk), part[c][h][n] ----------------
__global__ __launch_bounds__(256) void k_ktv(const u16* __restrict__ Kb,
                                             const u16* __restrict__ Vb,
                                             float* __restrict__ part) {
    __shared__ float Ks[64][68];                  // pad 68: write ~2-way, read 2-way
    __shared__ float Vs[64][68];
    const int tid = threadIdx.x;
    const int b = blockIdx.x >> 5, c = blockIdx.x & 31;
    const int i0 = (tid & 15) * 4;                // n (K-col) — inner/coalesced on store
    const int j0 = (tid >> 4) * 4;                // h (V-col)
    const int tr = tid >> 2, sc0 = (tid & 3) * 16;
    const size_t base = ((size_t)b * 2048 + c * 64) * 64;

    {
        const size_t src = base + (size_t)tr * 64 + sc0;
        const u32x4 ka = *(const u32x4*)(Kb + src);
        const u32x4 k2 = *(const u32x4*)(Kb + src + 8);
        const u32x4 va = *(const u32x4*)(Vb + src);
        const u32x4 v2 = *(const u32x4*)(Vb + src + 8);
        f32x4 t;
        t[0]=bflo(ka[0]); t[1]=bfhi(ka[0]); t[2]=bflo(ka[1]); t[3]=bfhi(ka[1]);
        *(f32x4*)&Ks[tr][sc0]      = t;
        t[0]=bflo(ka[2]); t[1]=bfhi(ka[2]); t[2]=bflo(ka[3]); t[3]=bfhi(ka[3]);
        *(f32x4*)&Ks[tr][sc0 + 4]  = t;
        t[0]=bflo(k2[0]); t[1]=bfhi(k2[0]); t[2]=bflo(k2[1]); t[3]=bfhi(k2[1]);
        *(f32x4*)&Ks[tr][sc0 + 8]  = t;
        t[0]=bflo(k2[2]); t[1]=bfhi(k2[2]); t[2]=bflo(k2[3]); t[3]=bfhi(k2[3]);
        *(f32x4*)&Ks[tr][sc0 + 12] = t;
        t[0]=bflo(va[0]); t[1]=bfhi(va[0]); t[2]=bflo(va[1]); t[3]=bfhi(va[1]);
        *(f32x4*)&Vs[tr][sc0]      = t;
        t[0]=bflo(va[2]); t[1]=bfhi(va[2]); t[2]=bflo(va[3]); t[3]=bfhi(va[3]);
        *(f32x4*)&Vs[tr][sc0 + 4]  = t;
        t[0]=bflo(v2[0]); t[1]=bfhi(v2[0]); t[2]=bflo(v2[1]); t[3]=bfhi(v2[1]);
        *(f32x4*)&Vs[tr][sc0 + 8]  = t;
        t[0]=bflo(v2[2]); t[1]=bfhi(v2[2]); t[2]=bflo(v2[3]); t[3]=bfhi(v2[3]);
        *(f32x4*)&Vs[tr][sc0 + 12] = t;
    }
    __syncthreads();

    f32x4 facc[4];
#pragma unroll
    for (int j = 0; j < 4; ++j)
#pragma unroll
        for (int q = 0; q < 4; ++q) facc[j][q] = 0.0f;

#pragma unroll 4
    for (int t = 0; t < 64; ++t) {
        const f32x4 kv = *(const f32x4*)&Ks[t][i0];
#pragma unroll
        for (int j = 0; j < 4; ++j) facc[j] += kv * Vs[t][j0 + j];
    }
    float* const P = part + (size_t)blockIdx.x * 4096;
#pragma unroll
    for (int j = 0; j < 4; ++j)
        *(f32x4*)&P[(j0 + j) * 64 + i0] = facc[j];   // part[c][h][n]
}

// ---------------- k_red: KtVT[b][o] = SCALE * sum_c part[b,c][o], bf16 ----------------
__global__ __launch_bounds__(256) void k_red(const float* __restrict__ part,
                                             u16* __restrict__ KtVT) {
    const int b = blockIdx.x >> 2;
    const int o0 = (blockIdx.x & 3) * 1024 + threadIdx.x * 4;
    const float* const Pb = part + (size_t)b * 32 * 4096;
    f32x4 s;
    s[0] = s[1] = s[2] = s[3] = 0.0f;
#pragma unroll 8
    for (int c = 0; c < 32; ++c) s += *(const f32x4*)(Pb + c * 4096 + o0);
    s *= 0.125f;                                   // SCALE = 64^-0.5
    u32x2 pk;
    pk[0] = (unsigned)f2bf(s[0]) | ((unsigned)f2bf(s[1]) << 16);
    pk[1] = (unsigned)f2bf(s[2]) | ((unsigned)f2bf(s[3]) << 16);
    *(u32x2*)(KtVT + (size_t)b * 4096 + o0) = pk;
}

// ---------------- k_out: out = Q @ KtV (K=64), fp32 out ----------------
__global__ __launch_bounds__(256) void k_out(const u16* __restrict__ Qb,
                                             const u16* __restrict__ KtVT,
                                             float* __restrict__ out) {
    const int tid = threadIdx.x;
    const int wave = tid >> 6, lane = tid & 63;
    const size_t m0 = (size_t)blockIdx.x * 64 + wave * 16;
    const int b = blockIdx.x >> 5;            // 32 blocks per batch
    const u16* const Bp = KtVT + (size_t)b * 4096;

    bf16x8 bfrag[2][4];
#pragma unroll
    for (int ks = 0; ks < 2; ++ks)
#pragma unroll
        for (int nt = 0; nt < 4; ++nt)
            bfrag[ks][nt] = *(const bf16x8*)(Bp + (nt * 16 + (lane & 15)) * 64 + ks * 32 + (lane >> 4) * 8);

    f32x4 acc[4];
#pragma unroll
    for (int nt = 0; nt < 4; ++nt)
#pragma unroll
        for (int r = 0; r < 4; ++r) acc[nt][r] = 0.0f;

#pragma unroll
    for (int ks = 0; ks < 2; ++ks) {
        const bf16x8 a = *(const bf16x8*)(Qb + (m0 + (lane & 15)) * 64 + ks * 32 + (lane >> 4) * 8);
#pragma unroll
        for (int nt = 0; nt < 4; ++nt)
            acc[nt] = __builtin_amdgcn_mfma_f32_16x16x32_bf16(a, bfrag[ks][nt], acc[nt], 0, 0, 0);
    }
#pragma unroll
    for (int nt = 0; nt < 4; ++nt)
#pragma unroll
        for (int rr = 0; rr < 4; ++rr)
            out[(m0 + (lane >> 4) * 4 + rr) * 64 + nt * 16 + (lane & 15)] = acc[nt][rr];
}

extern "C" void kernel_launch(void* const* d_in, const int* in_sizes, int n_in,
                              void* d_out, int out_size, void* d_ws, size_t ws_size,
                              hipStream_t stream) {
    (void)in_sizes; (void)n_in; (void)out_size; (void)ws_size;
    const float* x  = (const float*)d_in[0];
    const float* Wq = (const float*)d_in[1];
    const float* bq = (const float*)d_in[2];
    const float* Wk = (const float*)d_in[3];
    const float* bk = (const float*)d_in[4];
    const float* Wv = (const float*)d_in[5];
    const float* bv = (const float*)d_in[6];
    float* out = (float*)d_out;

    char* ws = (char*)d_ws;                       // layout (~42 MB total):
    u16*  WT   = (u16*)(ws);                      // 0x0000000: 384 KB  WT bf16 [192][1024]
    u16*  Qb   = (u16*)(ws + 0x60000);            // 0x0060000: 8 MB    Q bf16 [65536][64]
    u16*  Kb   = (u16*)(ws + 0x860000);           // 0x0860000: 8 MB    K bf16
    u16*  Vb   = (u16*)(ws + 0x1060000);          // 0x1060000: 8 MB    V bf16
    float* part= (float*)(ws + 0x1860000);        // 0x1860000: 16 MB   partials [1024][64][64] f32
    u16*  KtVT = (u16*)(ws + 0x2860000);          // 0x2860000: 256 KB  KtV^T bf16 [32][64][64]

    k_wt <<<192,  256, 0, stream>>>(Wq, Wk, Wv, WT);
    k_qkv<<<512,  512, 0, stream>>>(x, WT, bq, bk, bv, Qb, Kb, Vb);
    k_ktv<<<1024, 256, 0, stream>>>(Kb, Vb, part);
    k_red<<<128,  256, 0, stream>>>(part, KtVT);
    k_out<<<1024, 256, 0, stream>>>(Qb, KtVT, out);
}

// Round 3
// 92.329 us; speedup vs baseline: 1.4042x; 1.1392x over previous
//
#include <hip/hip_runtime.h>
#include <hip/hip_bf16.h>

// out = (Q K^T * SCALE) @ V  ==  Q @ (SCALE * K^T V)   (softmax discarded in ref)
// B=32, T=2048, E=1024, H=64.  M = B*T = 65536.
// Chain: k_wt (W transpose->bf16), k_qkv (QKV proj + fused per-block K^T V
// partials), k_red (reduce partials -> KtV^T bf16), k_out (Q @ KtV).

using bf16x8 = __attribute__((ext_vector_type(8))) short;
using f32x4  = __attribute__((ext_vector_type(4))) float;
using u32x4  = __attribute__((ext_vector_type(4))) unsigned int;
using u32x2  = __attribute__((ext_vector_type(2))) unsigned int;
using u16    = unsigned short;

__device__ __forceinline__ u16 f2bf(float f) {
    unsigned u = __builtin_bit_cast(unsigned, f);
    u += 0x7fffu + ((u >> 16) & 1u);          // RNE
    return (u16)(u >> 16);
}

#define G2L16(g, l) __builtin_amdgcn_global_load_lds(                         \
    (const __attribute__((address_space(1))) void*)(g),                       \
    (__attribute__((address_space(3))) void*)(l), 16, 0, 0)

// ---------------- k_wt: WT[n][e] = W*[e][n] as bf16 (LDS transpose) ----------------
__global__ __launch_bounds__(256) void k_wt(const float* __restrict__ Wq,
                                            const float* __restrict__ Wk,
                                            const float* __restrict__ Wv,
                                            u16* __restrict__ WT) {
    __shared__ float Wl[64][68];
    const int seg = blockIdx.x >> 4, chunk = blockIdx.x & 15;   // 48 blocks
    const float* W = (seg == 0) ? Wq : (seg == 1) ? Wk : Wv;
    const int e0 = chunk * 64;
    const int tid = threadIdx.x;
    const int lr = tid >> 4, lc = (tid & 15) * 4;
#pragma unroll
    for (int p = 0; p < 4; ++p)
        *(f32x4*)&Wl[lr + p * 16][lc] = *(const f32x4*)(W + (size_t)(e0 + lr + p * 16) * 64 + lc);
    __syncthreads();
    const int c = tid >> 2, eb = (tid & 3) * 16;
    u32x4 o0, o1;
#pragma unroll
    for (int q = 0; q < 4; ++q)
        o0[q] = (unsigned)f2bf(Wl[eb + 2 * q][c]) | ((unsigned)f2bf(Wl[eb + 2 * q + 1][c]) << 16);
#pragma unroll
    for (int q = 0; q < 4; ++q)
        o1[q] = (unsigned)f2bf(Wl[eb + 8 + 2 * q][c]) | ((unsigned)f2bf(Wl[eb + 9 + 2 * q][c]) << 16);
    u16* dst = WT + (size_t)(seg * 64 + c) * 1024 + e0 + eb;
    *(u32x4*)dst = o0;
    *(u32x4*)(dst + 8) = o1;
}

// ---------------- k_qkv: Q = x@Wq+bq (bf16 out) + fused partial K^T V ----------------
// 512 thr (8 waves), M-tile 64, N=192, BK=64, 16 k-chunks.
// LDS/buf: x f32 [64][64] (16 KB, swz ^((r&7)<<5)) + WT bf16 [192][64] (24 KB,
// swz ^((n&7)<<4)); dbuf = 80 KB -> 2 blocks/CU. gload_lds, counted vmcnt(5).
// Epilogue: K,V frags -> LDS K^T/V^T bf16 [64][72]; 2 MFMA/wave -> part[blk][hv][hk].
__global__ __launch_bounds__(512, 4) void k_qkv(const float* __restrict__ x,
                                                const u16* __restrict__ WT,
                                                const float* __restrict__ bq,
                                                const float* __restrict__ bk,
                                                const float* __restrict__ bv,
                                                u16* __restrict__ Qb,
                                                float* __restrict__ part) {
    __shared__ __align__(16) char lds[81920];
    const int tid  = threadIdx.x;
    const int wave = tid >> 6, lane = tid & 63;
    const int wr = wave >> 2, wc = wave & 3;      // 2M x 4N wave grid
    const size_t row0 = (size_t)blockIdx.x * 64;

    // staging sources (element offsets), fixed per lane; +k0 per chunk
    size_t xsrc[2]; int xdst[2];
#pragma unroll
    for (int i = 0; i < 2; ++i) {
        const int r  = (tid >> 4) + i * 32;
        const int cb = ((tid & 15) * 16) ^ ((r & 7) << 5);
        xsrc[i] = (row0 + r) * 1024 + (cb >> 2);
        xdst[i] = i * 8192 + wave * 1024;         // wave-uniform base; HW adds lane*16
    }
    size_t wsrc[3]; int wdst[3];
#pragma unroll
    for (int j = 0; j < 3; ++j) {
        const int n  = (tid >> 3) + j * 64;
        const int cb = ((tid & 7) * 16) ^ ((n & 7) << 4);
        wsrc[j] = (size_t)n * 1024 + (cb >> 1);
        wdst[j] = 16384 + j * 8192 + wave * 1024;
    }

    f32x4 acc[2][3];
#pragma unroll
    for (int m = 0; m < 2; ++m)
#pragma unroll
        for (int n = 0; n < 3; ++n)
#pragma unroll
            for (int r = 0; r < 4; ++r) acc[m][n][r] = 0.0f;

    // prologue: stage tile 0 into buf 0
#pragma unroll
    for (int i = 0; i < 2; ++i) G2L16(x + xsrc[i], lds + xdst[i]);
#pragma unroll
    for (int j = 0; j < 3; ++j) G2L16(WT + wsrc[j], lds + wdst[j]);

    for (int kc = 0; kc < 16; ++kc) {
        const int cur = kc & 1;
        if (kc < 15) {                            // stage next tile, keep 5 in flight
            const int k0 = (kc + 1) * 64;
            char* base = lds + (cur ^ 1) * 40960;
#pragma unroll
            for (int i = 0; i < 2; ++i) G2L16(x + xsrc[i] + k0, base + xdst[i]);
#pragma unroll
            for (int j = 0; j < 3; ++j) G2L16(WT + wsrc[j] + k0, base + wdst[j]);
            asm volatile("s_waitcnt vmcnt(5)" ::: "memory");   // current tile landed
        } else {
            asm volatile("s_waitcnt vmcnt(0)" ::: "memory");
        }
        __builtin_amdgcn_s_barrier();
        __builtin_amdgcn_sched_barrier(0);

        const char* xb = lds + cur * 40960;
        const char* wb = xb + 16384;
#pragma unroll
        for (int ks = 0; ks < 2; ++ks) {
            bf16x8 af[2];
#pragma unroll
            for (int m = 0; m < 2; ++m) {
                const int r = wr * 32 + m * 16 + (lane & 15);
                const int P = (r * 256 + ks * 128 + (lane >> 4) * 32) ^ ((r & 7) << 5);
                const f32x4 lo = *(const f32x4*)(xb + P);
                const f32x4 hi = *(const f32x4*)(xb + P + 16);
                u32x4 pk;
                pk[0] = (unsigned)f2bf(lo[0]) | ((unsigned)f2bf(lo[1]) << 16);
                pk[1] = (unsigned)f2bf(lo[2]) | ((unsigned)f2bf(lo[3]) << 16);
                pk[2] = (unsigned)f2bf(hi[0]) | ((unsigned)f2bf(hi[1]) << 16);
                pk[3] = (unsigned)f2bf(hi[2]) | ((unsigned)f2bf(hi[3]) << 16);
                af[m] = __builtin_bit_cast(bf16x8, pk);
            }
#pragma unroll
            for (int n = 0; n < 3; ++n) {
                const int nn = wc * 48 + n * 16 + (lane & 15);
                const int P  = (nn * 128 + ks * 64 + (lane >> 4) * 16) ^ ((nn & 7) << 4);
                const bf16x8 bfr = *(const bf16x8*)(wb + P);
                acc[0][n] = __builtin_amdgcn_mfma_f32_16x16x32_bf16(af[0], bfr, acc[0][n], 0, 0, 0);
                acc[1][n] = __builtin_amdgcn_mfma_f32_16x16x32_bf16(af[1], bfr, acc[1][n], 0, 0, 0);
            }
        }
        __builtin_amdgcn_sched_barrier(0);
        __builtin_amdgcn_s_barrier();             // all reads of buf[cur] done
    }

    // ---- epilogue: Q -> global; K,V -> LDS transposed bf16 tiles (+bias) ----
    // D-layout: col = lane&15, row = (lane>>4)*4 + rr
    u16* const Kt = (u16*)lds;                    // [64][72]  (h_k major)
    u16* const Vt = (u16*)(lds + 16384);          // [64][72]  (h_v major)
#pragma unroll
    for (int n = 0; n < 3; ++n) {
        const int ncol = wc * 48 + n * 16;
        const int seg = ncol >> 6;
        const int col = (ncol & 63) + (lane & 15);
        const float bias = ((seg == 0) ? bq : (seg == 1) ? bk : bv)[col];
#pragma unroll
        for (int m = 0; m < 2; ++m) {
            const int rloc = wr * 32 + m * 16 + ((lane >> 4) << 2);
            if (seg == 0) {
#pragma unroll
                for (int rr = 0; rr < 4; ++rr)
                    Qb[(row0 + rloc + rr) * 64 + col] = f2bf(acc[m][n][rr] + bias);
            } else {
                u16* const T = (seg == 1) ? Kt : Vt;
#pragma unroll
                for (int rr = 0; rr < 4; ++rr)
                    T[col * 72 + rloc + rr] = f2bf(acc[m][n][rr] + bias);
            }
        }
    }
    __syncthreads();

    // ---- fused K^T V partial: D[hv][hk] = sum_rows V[row][hv] * K[row][hk] ----
    float* const P = part + (size_t)blockIdx.x * 4096;
#pragma unroll
    for (int i = 0; i < 2; ++i) {
        const int f = wave * 2 + i;
        const int m0 = (f & 3) * 16;              // h_v
        const int n0 = (f >> 2) * 16;             // h_k
        f32x4 d;
        d[0] = d[1] = d[2] = d[3] = 0.0f;
#pragma unroll
        for (int ks = 0; ks < 2; ++ks) {
            const bf16x8 a = *(const bf16x8*)(Vt + (m0 + (lane & 15)) * 72 + ks * 32 + (lane >> 4) * 8);
            const bf16x8 b = *(const bf16x8*)(Kt + (n0 + (lane & 15)) * 72 + ks * 32 + (lane >> 4) * 8);
            d = __builtin_amdgcn_mfma_f32_16x16x32_bf16(a, b, d, 0, 0, 0);
        }
#pragma unroll
        for (int rr = 0; rr < 4; ++rr)
            P[(m0 + (lane >> 4) * 4 + rr) * 64 + n0 + (lane & 15)] = d[rr];
    }
}

// ---------------- k_red: KtVT[b][o] = SCALE * sum_c part[b*32+c][o], bf16 ----------------
__global__ __launch_bounds__(256) void k_red(const float* __restrict__ part,
                                             u16* __restrict__ KtVT) {
    const int b = blockIdx.x >> 2;
    const int o0 = (blockIdx.x & 3) * 1024 + threadIdx.x * 4;
    const float* const Pb = part + (size_t)b * 32 * 4096;
    f32x4 s;
    s[0] = s[1] = s[2] = s[3] = 0.0f;
#pragma unroll 8
    for (int c = 0; c < 32; ++c) s += *(const f32x4*)(Pb + c * 4096 + o0);
    s *= 0.125f;                                   // SCALE = 64^-0.5
    u32x2 pk;
    pk[0] = (unsigned)f2bf(s[0]) | ((unsigned)f2bf(s[1]) << 16);
    pk[1] = (unsigned)f2bf(s[2]) | ((unsigned)f2bf(s[3]) << 16);
    *(u32x2*)(KtVT + (size_t)b * 4096 + o0) = pk;
}

// ---------------- k_out: out = Q @ KtV (K=64), fp32 out ----------------
__global__ __launch_bounds__(256) void k_out(const u16* __restrict__ Qb,
                                             const u16* __restrict__ KtVT,
                                             float* __restrict__ out) {
    const int tid = threadIdx.x;
    const int wave = tid >> 6, lane = tid & 63;
    const size_t m0 = (size_t)blockIdx.x * 64 + wave * 16;
    const int b = blockIdx.x >> 5;            // 32 blocks per batch
    const u16* const Bp = KtVT + (size_t)b * 4096;

    bf16x8 bfrag[2][4];
#pragma unroll
    for (int ks = 0; ks < 2; ++ks)
#pragma unroll
        for (int nt = 0; nt < 4; ++nt)
            bfrag[ks][nt] = *(const bf16x8*)(Bp + (nt * 16 + (lane & 15)) * 64 + ks * 32 + (lane >> 4) * 8);

    f32x4 acc[4];
#pragma unroll
    for (int nt = 0; nt < 4; ++nt)
#pragma unroll
        for (int r = 0; r < 4; ++r) acc[nt][r] = 0.0f;

#pragma unroll
    for (int ks = 0; ks < 2; ++ks) {
        const bf16x8 a = *(const bf16x8*)(Qb + (m0 + (lane & 15)) * 64 + ks * 32 + (lane >> 4) * 8);
#pragma unroll
        for (int nt = 0; nt < 4; ++nt)
            acc[nt] = __builtin_amdgcn_mfma_f32_16x16x32_bf16(a, bfrag[ks][nt], acc[nt], 0, 0, 0);
    }
#pragma unroll
    for (int nt = 0; nt < 4; ++nt)
#pragma unroll
        for (int rr = 0; rr < 4; ++rr)
            out[(m0 + (lane >> 4) * 4 + rr) * 64 + nt * 16 + (lane & 15)] = acc[nt][rr];
}

extern "C" void kernel_launch(void* const* d_in, const int* in_sizes, int n_in,
                              void* d_out, int out_size, void* d_ws, size_t ws_size,
                              hipStream_t stream) {
    (void)in_sizes; (void)n_in; (void)out_size; (void)ws_size;
    const float* x  = (const float*)d_in[0];
    const float* Wq = (const float*)d_in[1];
    const float* bq = (const float*)d_in[2];
    const float* Wk = (const float*)d_in[3];
    const float* bk = (const float*)d_in[4];
    const float* Wv = (const float*)d_in[5];
    const float* bv = (const float*)d_in[6];
    float* out = (float*)d_out;

    char* ws = (char*)d_ws;                       // layout (~25 MB total):
    u16*  WT   = (u16*)(ws);                      // 0x0000000: 384 KB  WT bf16 [192][1024]
    u16*  Qb   = (u16*)(ws + 0x60000);            // 0x0060000: 8 MB    Q bf16 [65536][64]
    float* part= (float*)(ws + 0x860000);         // 0x0860000: 16 MB   partials [1024][64][64] f32
    u16*  KtVT = (u16*)(ws + 0x1860000);          // 0x1860000: 256 KB  KtV^T bf16 [32][64][64]

    k_wt <<<48,   256, 0, stream>>>(Wq, Wk, Wv, WT);
    k_qkv<<<1024, 512, 0, stream>>>(x, WT, bq, bk, bv, Qb, part);
    k_red<<<128,  256, 0, stream>>>(part, KtVT);
    k_out<<<1024, 256, 0, stream>>>(Qb, KtVT, out);
}